// Round 1
// baseline (338.641 us; speedup 1.0000x reference)
//
#include <hip/hip_runtime.h>

// Arnold cat map, 7 iterations fused into one affine permutation:
//   out[b,i,j,c] = in[b, (239*i + 169*j) % 1024, (338*i + 239*j) % 1024, c]
// (M = [[1,1],[2,1]]; M^7 = [[239,169],[338,239]] mod 1024, det = -1)
//
// Factored M^7 = A1 * A2 with A1 = [[0,169],[1,239]] (LDS-tiled pass),
// A2 = [[921,0],[983,1]] fused into A1's write side via 921^{-1} = 169 mod 1024
// and -983 = 41 mod 1024. Gives contiguous 768B read segments AND contiguous
// 768B write segments in a single pass (384 MiB total HBM traffic).

#define N_DIM 1024
#define MASKN 1023
#define TR 64               // tile extent in tmp-row (r) direction
#define TC 64               // tile extent in tmp-col (c) direction
#define LPITCH (TR * 3 + 1) // 193 floats: stride-193 -> bank stride 1, conflict-free

__global__ __launch_bounds__(256) void arnold_cat7_kernel(
    const float* __restrict__ in, float* __restrict__ out) {
    __shared__ float lds[TC * LPITCH]; // 64 * 193 * 4 = 49408 B

    const int tile = blockIdx.x;      // 0..255 : 16x16 tiles in tmp (r,c) space
    const int b    = blockIdx.y;      // 0..15  : batch
    const int r0   = (tile >> 4) * TR;
    const int c0   = (tile & 15) * TC;
    const int t    = threadIdx.x;     // 0..255

    const size_t img = (size_t)b * (size_t)(N_DIM * N_DIM * 3);
    const float* __restrict__ inb  = in + img;
    float* __restrict__ outb       = out + img;

    // ---- Read phase: tmp[r, c] = in[(169 c) & 1023, (r + 239 c) & 1023] ----
    // Wave-uniform segment (c_local), lane-contiguous dr -> 768 B coalesced reads.
#pragma unroll
    for (int k = 0; k < 16; ++k) {
        const int q       = t + 256 * k;   // 0..4095 pixel index in tile
        const int c_local = q >> 6;        // segment = c offset in tile
        const int dr      = q & 63;        // pixel within segment
        const int c       = c0 + c_local;
        const int R       = (169 * c) & MASKN;
        const int col     = (r0 + dr + 239 * c) & MASKN;
        const float* __restrict__ src = inb + ((size_t)R * N_DIM + (size_t)col) * 3;
        float* dst = &lds[c_local * LPITCH + dr * 3];
        dst[0] = src[0];
        dst[1] = src[1];
        dst[2] = src[2];
    }

    __syncthreads();

    // ---- Write phase: tmp[r, c] -> out[(169 r) & 1023, (c + 41*i) & 1023] ----
    // Wave-uniform segment (r_local), lane-contiguous dc -> 768 B coalesced writes.
#pragma unroll
    for (int k = 0; k < 16; ++k) {
        const int q       = t + 256 * k;
        const int r_local = q >> 6;        // segment = r offset in tile
        const int dc      = q & 63;        // pixel within segment
        const int r       = r0 + r_local;
        const int i       = (169 * r) & MASKN;
        const int j       = (c0 + dc + 41 * i) & MASKN;
        float* __restrict__ dst = outb + ((size_t)i * N_DIM + (size_t)j) * 3;
        const float* src = &lds[dc * LPITCH + r_local * 3];
        dst[0] = src[0];
        dst[1] = src[1];
        dst[2] = src[2];
    }
}

extern "C" void kernel_launch(void* const* d_in, const int* in_sizes, int n_in,
                              void* d_out, int out_size, void* d_ws, size_t ws_size,
                              hipStream_t stream) {
    (void)in_sizes; (void)n_in; (void)d_ws; (void)ws_size; (void)out_size;
    const float* in = (const float*)d_in[0];
    float* out      = (float*)d_out;
    dim3 grid(256, 16, 1); // 16x16 tiles per image, 16 batches
    dim3 block(256, 1, 1);
    hipLaunchKernelGGL(arnold_cat7_kernel, grid, block, 0, stream, in, out);
}

// Round 3
// 332.818 us; speedup vs baseline: 1.0175x; 1.0175x over previous
//
#include <hip/hip_runtime.h>

// Arnold cat, 7 iterations fused: out[b,i,j,:] = in[b, (239i+169j)%1024, (338i+239j)%1024, :]
// One LDS-tiled pass (64x64 pixel tiles). Tile param (dr, c_local):
//   read : row R=169c, cols (r0+239c)+dr   -> 768B contiguous per wave (lane=dr)
//   write: row i=169r, cols (c0+41i)+dc    -> 768B contiguous per wave (lane=dc)
// Round 1 verified this index math: absmax = 0.
//
// Round-3 = round-1 load path (plain per-lane loads; the size=12 LDS-DMA of
// round 2 silently failed -> NaN) + the two safe round-2 changes:
//  * 512-thread blocks: 24 waves/CU (was 12) for deeper VMEM queues.
//  * XCD swizzle: the 16 tiles sharing (batch, r0) write the SAME 64 output
//    rows -> same XCD so boundary partial lines merge in its L2.

#define NDIM    1024
#define MASKN   1023
#define LPITCHF 193   // floats per LDS segment slot: 64px*3 + 1 pad (bank stride 1)

__global__ __launch_bounds__(512) void arnold_cat7_kernel(
    const float* __restrict__ in, float* __restrict__ out) {
    __shared__ float lds[64 * LPITCHF];  // 49408 B -> 3 blocks/CU

    // ---- block swizzle: B -> (batch, r0, c0); same-(batch,r0) strips on one XCD
    const int B     = blockIdx.x;        // 0..4095
    const int xcd   = B & 7;
    const int q     = B >> 3;            // 0..511
    const int c0i   = q & 15;
    const int strip = ((q >> 4) << 3) | xcd;  // 0..255
    const int bimg  = strip >> 4;        // 0..15
    const int r0    = (strip & 15) << 6;
    const int c0    = c0i << 6;

    const int t  = threadIdx.x;          // 0..511
    const int w  = t >> 6;               // wave id 0..7
    const int dr = t & 63;               // lane

    const float* __restrict__ inb = in  + (size_t)bimg * (size_t)(NDIM * NDIM * 3);
    float* __restrict__ outb      = out + (size_t)bimg * (size_t)(NDIM * NDIM * 3);

    // ---- phase 1: global -> LDS, one 768B segment per wave-iter (8 iters)
#pragma unroll
    for (int k = 0; k < 8; ++k) {
        const int c_local = w + 8 * k;               // wave-uniform
        const int c   = c0 + c_local;
        const int R   = (169 * c) & MASKN;
        const int col = (r0 + dr + 239 * c) & MASKN; // lane-contiguous (mod wrap)
        const float* __restrict__ src = inb + (unsigned)(R * NDIM + col) * 3u;
        float* __restrict__ dst = &lds[c_local * LPITCHF + dr * 3];
        dst[0] = src[0];
        dst[1] = src[1];
        dst[2] = src[2];
    }
    __syncthreads();

    // ---- phase 2: LDS -> global, one 768B segment per wave-iter (8 iters)
#pragma unroll
    for (int k = 0; k < 8; ++k) {
        const int r_local = w + 8 * k;               // wave-uniform
        const int dc = dr;                           // lane
        const int r  = r0 + r_local;
        const int i  = (169 * r) & MASKN;
        const int j  = (c0 + dc + 41 * i) & MASKN;
        const float* __restrict__ s = &lds[dc * LPITCHF + r_local * 3]; // 2-way = free
        float* __restrict__ d = outb + (unsigned)(i * NDIM + j) * 3u;
        d[0] = s[0];
        d[1] = s[1];
        d[2] = s[2];
    }
}

extern "C" void kernel_launch(void* const* d_in, const int* in_sizes, int n_in,
                              void* d_out, int out_size, void* d_ws, size_t ws_size,
                              hipStream_t stream) {
    (void)in_sizes; (void)n_in; (void)d_ws; (void)ws_size; (void)out_size;
    const float* in = (const float*)d_in[0];
    float* out      = (float*)d_out;
    dim3 grid(4096, 1, 1);   // 16 batches x 16x16 tiles
    dim3 block(512, 1, 1);
    hipLaunchKernelGGL(arnold_cat7_kernel, grid, block, 0, stream, in, out);
}